// Round 10
// baseline (330.403 us; speedup 1.0000x reference)
//
#include <hip/hip_runtime.h>

typedef unsigned short u16;
typedef __attribute__((ext_vector_type(8))) short bf16x8;
typedef __attribute__((ext_vector_type(4))) short bf16x4;
typedef __attribute__((ext_vector_type(4))) float f32x4;

#define MFMA16(a, b, c) __builtin_amdgcn_mfma_f32_16x16x32_bf16(a, b, c, 0, 0, 0)

__device__ __forceinline__ u16 f2bf(float x) {
    unsigned u = __float_as_uint(x);
    return (u16)((u + 0x7fffu + ((u >> 16) & 1u)) >> 16);
}
__device__ __forceinline__ u16 f2bf_fast(float x) {  // round-half-up (P matrix only)
    return (u16)((__float_as_uint(x) + 0x8000u) >> 16);
}

// ---------------------------------------------------------------------------
// fp32 -> bf16 flat cast. n must be a multiple of 8*256.
// ---------------------------------------------------------------------------
__global__ __launch_bounds__(256) void castk(const float* __restrict__ src, u16* __restrict__ dst) {
    const int i = (blockIdx.x * 256 + threadIdx.x) * 8;
    float4 a = *(const float4*)(src + i);
    float4 b = *(const float4*)(src + i + 4);
    bf16x8 v;
    v[0] = (short)f2bf(a.x); v[1] = (short)f2bf(a.y);
    v[2] = (short)f2bf(a.z); v[3] = (short)f2bf(a.w);
    v[4] = (short)f2bf(b.x); v[5] = (short)f2bf(b.y);
    v[6] = (short)f2bf(b.z); v[7] = (short)f2bf(b.w);
    *(bf16x8*)(dst + i) = v;
}

// ---------------------------------------------------------------------------
// fp32 src[r][c] -> bf16 dst[c][r], 64x64 LDS tiles. grid R/64*C/64, block 256
// ---------------------------------------------------------------------------
__global__ __launch_bounds__(256) void tkern(const float* __restrict__ src, u16* __restrict__ dst,
                                             int R, int C) {
    const int tC = C >> 6;
    const int tr = (blockIdx.x / tC) << 6;
    const int tc = (blockIdx.x % tC) << 6;
    __shared__ u16 ls[64 * 68];
    const int tid = threadIdx.x;
#pragma unroll
    for (int rep = 0; rep < 2; ++rep) {
        const int f = tid * 8 + rep * 2048;
        const int r = f >> 6, c = f & 63;
        float4 a = *(const float4*)(src + (size_t)(tr + r) * C + tc + c);
        float4 b = *(const float4*)(src + (size_t)(tr + r) * C + tc + c + 4);
        bf16x4 lo, hi;
        lo[0] = (short)f2bf(a.x); lo[1] = (short)f2bf(a.y);
        lo[2] = (short)f2bf(a.z); lo[3] = (short)f2bf(a.w);
        hi[0] = (short)f2bf(b.x); hi[1] = (short)f2bf(b.y);
        hi[2] = (short)f2bf(b.z); hi[3] = (short)f2bf(b.w);
        *(bf16x4*)&ls[r * 68 + c] = lo;
        *(bf16x4*)&ls[r * 68 + c + 4] = hi;
    }
    __syncthreads();
#pragma unroll
    for (int rep = 0; rep < 2; ++rep) {
        const int f = tid * 8 + rep * 2048;
        const int rn = f >> 6, ck = f & 63;
        bf16x8 v;
#pragma unroll
        for (int j = 0; j < 8; ++j) v[j] = (short)ls[(ck + j) * 68 + rn];
        *(bf16x8*)(dst + (size_t)(tc + rn) * R + tr + ck) = v;
    }
}

// ---------------------------------------------------------------------------
// gemm_big: 256x256-tile GEMM for the QKV projection (MODE-0 semantics).
// C[m][n] = sum_k A[m][k]*Bt[n][k] + bias[n], M=8192, N=3072, K=1024.
// r10 rationale: the 128^2 gemm was OPERAND-TRAFFIC-BOUND, not schedule-bound
// (r9 dbuf ~null, matching m99/m100): 1536 blocks x 0.5MB = 768 MB of tile
// re-reads; FLOP/B=65 -> ~470 TF observed. 256^2 doubles FLOP/B to 130 and
// halves traffic to 384 MB. Schedule is the r9-proven one (single barrier
// per K-step, stage-ahead into the other dbuf slot, global_load_lds 16B).
// 512 threads = 8 waves (2M x 4N), per-wave 128x64 output, acc[8][4].
// LDS 64 KB (2 blocks/CU). Grid 32x12=384 (1.5/CU -- acceptable while
// traffic-bound). XCD chunking: xcd owns 4 contiguous mt -> its A-slice
// (4x256x1024x2B = 2MB) is L2-resident.
// NO 2nd launch_bounds arg (hard VGPR cap lesson, r1/r3).
// ---------------------------------------------------------------------------
__global__ __launch_bounds__(512) void gemm_big(const u16* __restrict__ A, const u16* __restrict__ Bt,
                                                const float* __restrict__ bias,
                                                u16* __restrict__ Qo, u16* __restrict__ Ko,
                                                u16* __restrict__ Vo) {
    constexpr int Kd = 1024;
    const int tid = threadIdx.x;
    const int lane = tid & 63, wave = tid >> 6;  // 8 waves
    const int wm = wave >> 2, wn = wave & 3;     // 2 x 4
    const int lr = lane & 15, lg = lane >> 4;
    const int bid = blockIdx.x;                  // 0..383
    const int xcd = bid & 7;
    const int cc = bid >> 3;                     // 0..47
    const int mt = xcd * 4 + cc / 12;            // 0..31, 4 contiguous mt per XCD
    const int nt = cc % 12;                      // 0..11
    const int mbase = mt << 8, nbase = nt << 8;
    __shared__ u16 As[2][256 * 32];
    __shared__ u16 Bs[2][256 * 32];
    f32x4 acc[8][4];
#pragma unroll
    for (int i = 0; i < 8; ++i)
#pragma unroll
        for (int j = 0; j < 4; ++j) acc[i][j] = {0.f, 0.f, 0.f, 0.f};

    // staging: thread t covers elements t*8 (rows 0..127) and 4096+t*8
    // (rows 128..255) of the [256][32] tile; 16B loads, linear dest.
    const int row0 = tid >> 2;
    const int col0 = (tid & 3) * 8;
    auto stage = [&](int sel, int kb) {
        __builtin_amdgcn_global_load_lds(
            (const __attribute__((address_space(1))) void*)(A + (size_t)(mbase + row0) * Kd + kb + col0),
            (__attribute__((address_space(3))) void*)(&As[sel][tid * 8]), 16, 0, 0);
        __builtin_amdgcn_global_load_lds(
            (const __attribute__((address_space(1))) void*)(A + (size_t)(mbase + 128 + row0) * Kd + kb + col0),
            (__attribute__((address_space(3))) void*)(&As[sel][4096 + tid * 8]), 16, 0, 0);
        __builtin_amdgcn_global_load_lds(
            (const __attribute__((address_space(1))) void*)(Bt + (size_t)(nbase + row0) * Kd + kb + col0),
            (__attribute__((address_space(3))) void*)(&Bs[sel][tid * 8]), 16, 0, 0);
        __builtin_amdgcn_global_load_lds(
            (const __attribute__((address_space(1))) void*)(Bt + (size_t)(nbase + 128 + row0) * Kd + kb + col0),
            (__attribute__((address_space(3))) void*)(&Bs[sel][4096 + tid * 8]), 16, 0, 0);
    };

    stage(0, 0);
    for (int kb = 0; kb < Kd; kb += 32) {
        const int cur = (kb >> 5) & 1;
        __syncthreads();  // vmcnt(0) drain precedes barrier -> buf[cur] ready;
                          // all waves done reading buf[cur^1]
        if (kb + 32 < Kd) stage(cur ^ 1, kb + 32);
        bf16x8 af[8], bfr[4];
#pragma unroll
        for (int i = 0; i < 8; ++i)
            af[i] = *(const bf16x8*)&As[cur][(wm * 128 + i * 16 + lr) * 32 + lg * 8];
#pragma unroll
        for (int j = 0; j < 4; ++j)
            bfr[j] = *(const bf16x8*)&Bs[cur][(wn * 64 + j * 16 + lr) * 32 + lg * 8];
#pragma unroll
        for (int i = 0; i < 8; ++i)
#pragma unroll
            for (int j = 0; j < 4; ++j) acc[i][j] = MFMA16(af[i], bfr[j], acc[i][j]);
    }

    const float QSCALE = 0.1803368801111137f;  // 0.125 * log2(e), folded into Q
#pragma unroll
    for (int j = 0; j < 4; ++j) {
        const int n = nbase + wn * 64 + j * 16 + lr;
        const float bj = bias[n];
        const int three = n >> 10;
        const int h = (n >> 6) & 15;
        const int d = n & 63;
#pragma unroll
        for (int i = 0; i < 8; ++i) {
#pragma unroll
            for (int r = 0; r < 4; ++r) {
                const int m = mbase + wm * 128 + i * 16 + lg * 4 + r;
                const int b = m >> 11, t = m & 2047;
                const int bh = (b << 4) + h;
                const float val = acc[i][j][r] + bj;
                if (three == 0)
                    Qo[(((size_t)bh << 11) + t) * 64 + d] = f2bf(val * QSCALE);
                else if (three == 1)
                    Ko[(((size_t)bh << 11) + t) * 64 + d] = f2bf(val);
                else
                    Vo[(((size_t)bh << 6) + d) * 2048 + t] = f2bf(val);
            }
        }
    }
}

// ---------------------------------------------------------------------------
// GEMM (128^2, r9 schedule): kept for MODE 1 (out-proj, N=1024, fp32 store).
// ---------------------------------------------------------------------------
__global__ __launch_bounds__(256) void gemm_k1(const u16* __restrict__ A, const u16* __restrict__ Bt,
                                               const float* __restrict__ bias, float* __restrict__ Of) {
    constexpr int Kd = 1024;
    const int tid = threadIdx.x;
    const int lane = tid & 63, wave = tid >> 6;
    const int wm = wave >> 1, wn = wave & 1;
    const int lr = lane & 15, lg = lane >> 4;
    const int bid = blockIdx.x;
    const int xcd = bid & 7;
    const int cc = bid >> 3;
    const int mt = xcd * 8 + (cc & 7);   // contiguous 8-mtile slice per XCD
    const int nt = cc >> 3;
    const int mbase = mt << 7, nbase = nt << 7;
    __shared__ u16 As[2][128 * 32];
    __shared__ u16 Bs[2][128 * 32];
    f32x4 acc[4][4];
#pragma unroll
    for (int i = 0; i < 4; ++i)
#pragma unroll
        for (int j = 0; j < 4; ++j) acc[i][j] = {0.f, 0.f, 0.f, 0.f};

    auto stage = [&](int sel, int kb) {
#pragma unroll
        for (int rep = 0; rep < 2; ++rep) {
            const int f = tid * 8 + rep * 2048;
            const int r = f >> 5, c = f & 31;
            __builtin_amdgcn_global_load_lds(
                (const __attribute__((address_space(1))) void*)(A + (size_t)(mbase + r) * Kd + kb + c),
                (__attribute__((address_space(3))) void*)(&As[sel][f]), 16, 0, 0);
            __builtin_amdgcn_global_load_lds(
                (const __attribute__((address_space(1))) void*)(Bt + (size_t)(nbase + r) * Kd + kb + c),
                (__attribute__((address_space(3))) void*)(&Bs[sel][f]), 16, 0, 0);
        }
    };

    stage(0, 0);
    for (int kb = 0; kb < Kd; kb += 32) {
        const int cur = (kb >> 5) & 1;
        __syncthreads();
        if (kb + 32 < Kd) stage(cur ^ 1, kb + 32);
        bf16x8 af[4], bfr[4];
#pragma unroll
        for (int i = 0; i < 4; ++i)
            af[i] = *(const bf16x8*)&As[cur][(wm * 64 + i * 16 + lr) * 32 + lg * 8];
#pragma unroll
        for (int j = 0; j < 4; ++j)
            bfr[j] = *(const bf16x8*)&Bs[cur][(wn * 64 + j * 16 + lr) * 32 + lg * 8];
#pragma unroll
        for (int i = 0; i < 4; ++i)
#pragma unroll
            for (int j = 0; j < 4; ++j) acc[i][j] = MFMA16(af[i], bfr[j], acc[i][j]);
    }

#pragma unroll
    for (int j = 0; j < 4; ++j) {
        const int n = nbase + wn * 64 + j * 16 + lr;
        const float bj = bias[n];
#pragma unroll
        for (int i = 0; i < 4; ++i) {
#pragma unroll
            for (int r = 0; r < 4; ++r) {
                const int m = mbase + wm * 64 + i * 16 + lg * 4 + r;
                Of[((size_t)m << 10) + n] = acc[i][j][r] + bj;
            }
        }
    }
}

// ---------------------------------------------------------------------------
// Causal flash attention, LDS-staged K/V, double-buffered (r6 structure +
// r8 local grafts: exact defer-rescale, max3-triple rmax, pairwise rsum).
// Measured 114.5us (r8) / 124.4 (r9, same code -- container noise ~8%).
// UNCHANGED this round (control).
// NO 2nd launch_bounds arg (hard VGPR cap: r1 (256,4)->64, r3 (128,2)->128,
// both catastrophic spills).
// ---------------------------------------------------------------------------
__global__ __launch_bounds__(256) void flash_attn(const u16* __restrict__ Q, const u16* __restrict__ Kg,
                                                  const u16* __restrict__ Vt, u16* __restrict__ Aout) {
    const int tid = threadIdx.x;
    const int lane = tid & 63, wave = tid >> 6;  // wave 0..3
    const int lr = lane & 15, lg = lane >> 4;
    const int bid = blockIdx.x;                  // 0..1023
    const int swz = (bid & 7) * 128 + (bid >> 3);
    const int bh = swz >> 4;     // 0..63
    const int bx = swz & 15;     // 0..15
    const int b = bh >> 4, h = bh & 15;
    const size_t base = (size_t)bh << 17;  // bh * 2048 * 64

    const int qb_hi = 16 + bx;
    const int qb_lo = 15 - bx;

    __shared__ u16 Ks[2][64 * 64];     // K tile  [kv_local][d], chunk-swizzled
    __shared__ u16 Vs[2][64 * 64];     // Vt tile [d][kv_local], chunk-swizzled
    __shared__ u16 Ps[4][16 * 64];     // per-wave P scratch, chunk-XOR-swizzled

    // subtile q-bases: 0 = hi slice, 1 = lo slice (16 rows each)
    int qbase[2];
    qbase[0] = qb_hi * 64 + wave * 16;
    qbase[1] = qb_lo * 64 + wave * 16;

    bf16x8 qf[2][2];
#pragma unroll
    for (int st = 0; st < 2; ++st) {
        const u16* p = Q + base + (size_t)(qbase[st] + lr) * 64;
        qf[st][0] = *(const bf16x8*)(p + lg * 8);
        qf[st][1] = *(const bf16x8*)(p + 32 + lg * 8);
    }

    f32x4 o[2][4];
#pragma unroll
    for (int st = 0; st < 2; ++st)
#pragma unroll
        for (int dt = 0; dt < 4; ++dt) o[st][dt] = {0.f, 0.f, 0.f, 0.f};
    float m_[2] = {-INFINITY, -INFINITY};
    float l_[2] = {0.f, 0.f};

    // staging geometry (kt-invariant): thread stages 16B chunks.
    // dest (linear): byte f = (tid + rep*256)*16 -> row = f>>7, chunk c =
    // (f>>4)&7.  source chunk cc = c ^ (row&7)  (rule 21 pre-swizzle).
    const int f0 = tid * 16;
    const int row0 = f0 >> 7, c0 = (f0 >> 4) & 7;
    const int cc0 = c0 ^ (row0 & 7);
    const int f1 = (tid + 256) * 16;
    const int row1 = f1 >> 7, c1 = (f1 >> 4) & 7;
    const int cc1 = c1 ^ (row1 & 7);

    const int xr = lr & 7;  // read-side XOR key

    auto stage = [&](int sel, int kt) {
        const size_t krow = base + (size_t)(kt * 64) * 64;
        __builtin_amdgcn_global_load_lds(
            (const __attribute__((address_space(1))) void*)(Kg + krow + (size_t)row0 * 64 + cc0 * 8),
            (__attribute__((address_space(3))) void*)(&Ks[sel][tid * 8]), 16, 0, 0);
        __builtin_amdgcn_global_load_lds(
            (const __attribute__((address_space(1))) void*)(Kg + krow + (size_t)row1 * 64 + cc1 * 8),
            (__attribute__((address_space(3))) void*)(&Ks[sel][2048 + tid * 8]), 16, 0, 0);
        __builtin_amdgcn_global_load_lds(
            (const __attribute__((address_space(1))) void*)(Vt + base + (size_t)row0 * 2048 + kt * 64 + cc0 * 8),
            (__attribute__((address_space(3))) void*)(&Vs[sel][tid * 8]), 16, 0, 0);
        __builtin_amdgcn_global_load_lds(
            (const __attribute__((address_space(1))) void*)(Vt + base + (size_t)row1 * 2048 + kt * 64 + cc1 * 8),
            (__attribute__((address_space(3))) void*)(&Vs[sel][2048 + tid * 8]), 16, 0, 0);
    };

    auto process = [&](int sel, int st, bool diag, int kt) {
        // S^T[kv][q] = K * Q^T  (kv = kt*64 + rt*16 + lg*4 + reg, q = lr)
        f32x4 s[4];
#pragma unroll
        for (int rt = 0; rt < 4; ++rt) {
            const int krow = rt * 16 + lr;
            const bf16x8 k0 = *(const bf16x8*)&Ks[sel][krow * 64 + ((lg) ^ xr) * 8];
            const bf16x8 k1 = *(const bf16x8*)&Ks[sel][krow * 64 + ((lg + 4) ^ xr) * 8];
            f32x4 z = {0.f, 0.f, 0.f, 0.f};
            z = MFMA16(k0, qf[st][0], z);
            z = MFMA16(k1, qf[st][1], z);
            s[rt] = z;
        }
        if (diag) {
            const int q_glob = qbase[st] + lr;
#pragma unroll
            for (int rt = 0; rt < 4; ++rt)
#pragma unroll
                for (int r = 0; r < 4; ++r) {
                    const int kv = kt * 64 + rt * 16 + lg * 4 + r;
                    if (kv > q_glob) s[rt][r] = -INFINITY;
                }
        }
        // rmax via max3-friendly triples
        const float t0 = fmaxf(fmaxf(s[0][0], s[0][1]), s[0][2]);
        const float t1 = fmaxf(fmaxf(s[0][3], s[1][0]), s[1][1]);
        const float t2 = fmaxf(fmaxf(s[1][2], s[1][3]), s[2][0]);
        const float t3 = fmaxf(fmaxf(s[2][1], s[2][2]), s[2][3]);
        const float t4 = fmaxf(fmaxf(s[3][0], s[3][1]), s[3][2]);
        float rmax = fmaxf(fmaxf(fmaxf(t0, t1), t2), fmaxf(fmaxf(t3, t4), s[3][3]));
        rmax = fmaxf(rmax, __shfl_xor(rmax, 16));
        rmax = fmaxf(rmax, __shfl_xor(rmax, 32));

        if (!__all(rmax <= m_[st])) {  // exact skip: max didn't grow -> alpha==1
            const float m_new = fmaxf(m_[st], rmax);
            const float alpha = exp2f(m_[st] - m_new);
            float aq[4];
#pragma unroll
            for (int r = 0; r < 4; ++r) aq[r] = __shfl(alpha, (lane & 48) + lg * 4 + r);
#pragma unroll
            for (int dt = 0; dt < 4; ++dt)
#pragma unroll
                for (int r = 0; r < 4; ++r) o[st][dt][r] *= aq[r];
            l_[st] *= alpha;
            m_[st] = m_new;
        }

#pragma unroll
        for (int rt = 0; rt < 4; ++rt)
#pragma unroll
            for (int r = 0; r < 4; ++r) s[rt][r] = exp2f(s[rt][r] - m_[st]);
        // pairwise rsum tree
        const float u0 = (s[0][0] + s[0][1]) + (s[0][2] + s[0][3]);
        const float u1 = (s[1][0] + s[1][1]) + (s[1][2] + s[1][3]);
        const float u2 = (s[2][0] + s[2][1]) + (s[2][2] + s[2][3]);
        const float u3 = (s[3][0] + s[3][1]) + (s[3][2] + s[3][3]);
        float rsum = (u0 + u1) + (u2 + u3);
        rsum += __shfl_xor(rsum, 16);
        rsum += __shfl_xor(rsum, 32);
        l_[st] += rsum;

        // P (C-layout) -> LDS (XOR-swizzled rows of 8x16B chunks) -> A-frags
        u16* psb = &Ps[wave][0];
#pragma unroll
        for (int rt = 0; rt < 4; ++rt) {
            bf16x4 pk;
#pragma unroll
            for (int r = 0; r < 4; ++r) pk[r] = (short)f2bf_fast(s[rt][r]);
            *(bf16x4*)&psb[lr * 64 + (((rt * 2 + (lg >> 1)) ^ xr) << 3) + ((lg & 1) << 2)] = pk;
        }

        const bf16x8 pf0 = *(const bf16x8*)&psb[lr * 64 + ((lg ^ xr) << 3)];
        const bf16x8 pf1 = *(const bf16x8*)&psb[lr * 64 + (((4 + lg) ^ xr) << 3)];
#pragma unroll
        for (int dt = 0; dt < 4; ++dt) {
            const int vrow = dt * 16 + lr;
            const bf16x8 v0 = *(const bf16x8*)&Vs[sel][vrow * 64 + ((lg) ^ xr) * 8];
            const bf16x8 v1 = *(const bf16x8*)&Vs[sel][vrow * 64 + ((lg + 4) ^ xr) * 8];
            o[st][dt] = MFMA16(pf0, v0, o[st][dt]);
            o[st][dt] = MFMA16(pf1, v1, o[st][dt]);
        }
    };

    stage(0, 0);
    for (int kt = 0; kt <= qb_hi; ++kt) {
        const int cur = kt & 1;
        __syncthreads();  // vmcnt(0) drain precedes barrier -> buf[cur] ready;
                          // all waves done reading buf[cur^1]
        if (kt < qb_hi) stage(cur ^ 1, kt + 1);
        process(cur, 0, kt == qb_hi, kt);
        if (kt <= qb_lo) process(cur, 1, kt == qb_lo, kt);
    }

#pragma unroll
    for (int st = 0; st < 2; ++st) {
        const float linv = 1.f / l_[st];
        float lq[4];
#pragma unroll
        for (int r = 0; r < 4; ++r) lq[r] = __shfl(linv, (lane & 48) + lg * 4 + r);
#pragma unroll
        for (int dt = 0; dt < 4; ++dt)
#pragma unroll
            for (int r = 0; r < 4; ++r) {
                const int t = qbase[st] + lg * 4 + r;
                Aout[(((size_t)(b << 11) + t) << 10) + h * 64 + dt * 16 + lr] =
                    f2bf(o[st][dt][r] * lq[r]);
            }
    }
}

// ---------------------------------------------------------------------------
extern "C" void kernel_launch(void* const* d_in, const int* in_sizes, int n_in,
                              void* d_out, int out_size, void* d_ws, size_t ws_size,
                              hipStream_t stream) {
    (void)in_sizes; (void)n_in; (void)out_size; (void)ws_size;
    const float* x    = (const float*)d_in[0];
    const float* Wqkv = (const float*)d_in[2];
    const float* bqkv = (const float*)d_in[3];
    const float* Wout = (const float*)d_in[4];
    const float* bout = (const float*)d_in[5];
    float* out = (float*)d_out;

    char* ws = (char*)d_ws;
    u16* WqkvT = (u16*)(ws);                    //  6 MB: [3072][1024] bf16
    u16* WoutT = (u16*)(ws + 6291456);          //  2 MB: [1024][1024] bf16
    u16* xb    = (u16*)(ws + 8388608);          // 16 MB: [8192][1024] bf16
    u16* Qb    = (u16*)(ws + 25165824);         // 16 MB: [BH][T][D]
    u16* Kb    = (u16*)(ws + 41943040);         // 16 MB: [BH][T][D]
    u16* Vtb   = (u16*)(ws + 58720256);         // 16 MB: [BH][D][T]
    u16* Ab    = (u16*)(ws + 75497472);         // 16 MB: [B][T][C]

    castk<<<dim3(4096), 256, 0, stream>>>(x, xb);
    tkern<<<dim3(16 * 48), 256, 0, stream>>>(Wqkv, WqkvT, 1024, 3072);
    tkern<<<dim3(16 * 16), 256, 0, stream>>>(Wout, WoutT, 1024, 1024);
    gemm_big<<<dim3(384), 512, 0, stream>>>(xb, WqkvT, bqkv, Qb, Kb, Vtb);
    flash_attn<<<dim3(1024), 256, 0, stream>>>(Qb, Kb, Vtb, Ab);
    gemm_k1<<<dim3(64 * 8), 256, 0, stream>>>(Ab, WoutT, bout, out);
}

// Round 11
// 317.240 us; speedup vs baseline: 1.0415x; 1.0415x over previous
//
#include <hip/hip_runtime.h>

typedef unsigned short u16;
typedef __attribute__((ext_vector_type(8))) short bf16x8;
typedef __attribute__((ext_vector_type(4))) short bf16x4;
typedef __attribute__((ext_vector_type(4))) float f32x4;

#define MFMA16(a, b, c) __builtin_amdgcn_mfma_f32_16x16x32_bf16(a, b, c, 0, 0, 0)

__device__ __forceinline__ u16 f2bf(float x) {
    unsigned u = __float_as_uint(x);
    return (u16)((u + 0x7fffu + ((u >> 16) & 1u)) >> 16);
}

// ---------------------------------------------------------------------------
// fp32 -> bf16 flat cast. n must be a multiple of 8*256.
// ---------------------------------------------------------------------------
__global__ __launch_bounds__(256) void castk(const float* __restrict__ src, u16* __restrict__ dst) {
    const int i = (blockIdx.x * 256 + threadIdx.x) * 8;
    float4 a = *(const float4*)(src + i);
    float4 b = *(const float4*)(src + i + 4);
    bf16x8 v;
    v[0] = (short)f2bf(a.x); v[1] = (short)f2bf(a.y);
    v[2] = (short)f2bf(a.z); v[3] = (short)f2bf(a.w);
    v[4] = (short)f2bf(b.x); v[5] = (short)f2bf(b.y);
    v[6] = (short)f2bf(b.z); v[7] = (short)f2bf(b.w);
    *(bf16x8*)(dst + i) = v;
}

// ---------------------------------------------------------------------------
// fp32 src[r][c] -> bf16 dst[c][r], 64x64 LDS tiles. grid R/64*C/64, block 256
// ---------------------------------------------------------------------------
__global__ __launch_bounds__(256) void tkern(const float* __restrict__ src, u16* __restrict__ dst,
                                             int R, int C) {
    const int tC = C >> 6;
    const int tr = (blockIdx.x / tC) << 6;
    const int tc = (blockIdx.x % tC) << 6;
    __shared__ u16 ls[64 * 68];
    const int tid = threadIdx.x;
#pragma unroll
    for (int rep = 0; rep < 2; ++rep) {
        const int f = tid * 8 + rep * 2048;
        const int r = f >> 6, c = f & 63;
        float4 a = *(const float4*)(src + (size_t)(tr + r) * C + tc + c);
        float4 b = *(const float4*)(src + (size_t)(tr + r) * C + tc + c + 4);
        bf16x4 lo, hi;
        lo[0] = (short)f2bf(a.x); lo[1] = (short)f2bf(a.y);
        lo[2] = (short)f2bf(a.z); lo[3] = (short)f2bf(a.w);
        hi[0] = (short)f2bf(b.x); hi[1] = (short)f2bf(b.y);
        hi[2] = (short)f2bf(b.z); hi[3] = (short)f2bf(b.w);
        *(bf16x4*)&ls[r * 68 + c] = lo;
        *(bf16x4*)&ls[r * 68 + c + 4] = hi;
    }
    __syncthreads();
#pragma unroll
    for (int rep = 0; rep < 2; ++rep) {
        const int f = tid * 8 + rep * 2048;
        const int rn = f >> 6, ck = f & 63;
        bf16x8 v;
#pragma unroll
        for (int j = 0; j < 8; ++j) v[j] = (short)ls[(ck + j) * 68 + rn];
        *(bf16x8*)(dst + (size_t)(tc + rn) * R + tr + ck) = v;
    }
}

// ---------------------------------------------------------------------------
// GEMM: C[m][n] = sum_k A[m][k] * Bt[n][k] + bias[n].  M=8192, K=1024, bf16.
// MODE 0: N=3072, scatter to Q(scaled)[BH][T][D], K[BH][T][D], V^T[BH][D][T].
// MODE 1: N=1024, fp32 store to Of[M][N].
// r11: REVERTED to the r9 128^2 dbuf version (best total, 317). The r10
// 256^2 tile was neutral-to-negative (occupancy 2/CU, 1.5 sched rounds) --
// three different gemm0 structures all land at the same "rest" time, so
// gemm0 is not schedule- or tile-traffic-bound at this scale.
// ---------------------------------------------------------------------------
template <int MODE>
__global__ __launch_bounds__(256) void gemm_k(const u16* __restrict__ A, const u16* __restrict__ Bt,
                                              const float* __restrict__ bias,
                                              u16* __restrict__ Qo, u16* __restrict__ Ko,
                                              u16* __restrict__ Vo, float* __restrict__ Of) {
    constexpr int Kd = 1024;
    const int tid = threadIdx.x;
    const int lane = tid & 63, wave = tid >> 6;
    const int wm = wave >> 1, wn = wave & 1;
    const int lr = lane & 15, lg = lane >> 4;
    const int bid = blockIdx.x;
    const int xcd = bid & 7;
    const int cc = bid >> 3;
    const int mt = xcd * 8 + (cc & 7);   // contiguous 8-mtile slice per XCD
    const int nt = cc >> 3;
    const int mbase = mt << 7, nbase = nt << 7;
    __shared__ u16 As[2][128 * 32];
    __shared__ u16 Bs[2][128 * 32];
    f32x4 acc[4][4];
#pragma unroll
    for (int i = 0; i < 4; ++i)
#pragma unroll
        for (int j = 0; j < 4; ++j) acc[i][j] = {0.f, 0.f, 0.f, 0.f};

    auto stage = [&](int sel, int kb) {
#pragma unroll
        for (int rep = 0; rep < 2; ++rep) {
            const int f = tid * 8 + rep * 2048;
            const int r = f >> 5, c = f & 31;
            __builtin_amdgcn_global_load_lds(
                (const __attribute__((address_space(1))) void*)(A + (size_t)(mbase + r) * Kd + kb + c),
                (__attribute__((address_space(3))) void*)(&As[sel][f]), 16, 0, 0);
            __builtin_amdgcn_global_load_lds(
                (const __attribute__((address_space(1))) void*)(Bt + (size_t)(nbase + r) * Kd + kb + c),
                (__attribute__((address_space(3))) void*)(&Bs[sel][f]), 16, 0, 0);
        }
    };

    stage(0, 0);
    for (int kb = 0; kb < Kd; kb += 32) {
        const int cur = (kb >> 5) & 1;
        __syncthreads();  // vmcnt(0) drain precedes barrier -> buf[cur] ready;
                          // all waves done reading buf[cur^1]
        if (kb + 32 < Kd) stage(cur ^ 1, kb + 32);
        bf16x8 af[4], bfr[4];
#pragma unroll
        for (int i = 0; i < 4; ++i)
            af[i] = *(const bf16x8*)&As[cur][(wm * 64 + i * 16 + lr) * 32 + lg * 8];
#pragma unroll
        for (int j = 0; j < 4; ++j)
            bfr[j] = *(const bf16x8*)&Bs[cur][(wn * 64 + j * 16 + lr) * 32 + lg * 8];
#pragma unroll
        for (int i = 0; i < 4; ++i)
#pragma unroll
            for (int j = 0; j < 4; ++j) acc[i][j] = MFMA16(af[i], bfr[j], acc[i][j]);
    }

    const float QSCALE = 0.1803368801111137f;  // 0.125 * log2(e), folded into Q
#pragma unroll
    for (int j = 0; j < 4; ++j) {
        const int n = nbase + wn * 64 + j * 16 + lr;
        const float bj = bias[n];
        if (MODE == 0) {
            const int three = n >> 10;
            const int h = (n >> 6) & 15;
            const int d = n & 63;
#pragma unroll
            for (int i = 0; i < 4; ++i) {
#pragma unroll
                for (int r = 0; r < 4; ++r) {
                    const int m = mbase + wm * 64 + i * 16 + lg * 4 + r;
                    const int b = m >> 11, t = m & 2047;
                    const int bh = (b << 4) + h;
                    const float val = acc[i][j][r] + bj;
                    if (three == 0)
                        Qo[(((size_t)bh << 11) + t) * 64 + d] = f2bf(val * QSCALE);
                    else if (three == 1)
                        Ko[(((size_t)bh << 11) + t) * 64 + d] = f2bf(val);
                    else
                        Vo[(((size_t)bh << 6) + d) * 2048 + t] = f2bf(val);
                }
            }
        } else {
#pragma unroll
            for (int i = 0; i < 4; ++i) {
#pragma unroll
                for (int r = 0; r < 4; ++r) {
                    const int m = mbase + wm * 64 + i * 16 + lg * 4 + r;
                    Of[((size_t)m << 10) + n] = acc[i][j][r] + bj;
                }
            }
        }
    }
}

// ---------------------------------------------------------------------------
// Causal flash attention, LDS-staged K/V, double-buffered (r6 structure +
// r8 grafts). r11 change: P fp32->bf16 conversion via v_cvt_pk_bf16_f32
// inline asm (T12 recipe; no builtin on gfx950). One instruction packs 2
// f32 -> u32 of 2 bf16 (RNE), replacing the scalar f2bf_fast + manual
// bf16x4 pack (~44 VALU ops -> 8 per process). VALU audit: process was
// ~140 VALU vs 16 MFMA (280cy vs 80cy) = the 58%-VALUBusy/12.6%-MfmaUtil
// signature; the convert+pack block was the largest reducible chunk.
// NO 2nd launch_bounds arg (hard VGPR cap: r1 (256,4)->64, r3 (128,2)->128,
// both catastrophic spills).
// ---------------------------------------------------------------------------
__global__ __launch_bounds__(256) void flash_attn(const u16* __restrict__ Q, const u16* __restrict__ Kg,
                                                  const u16* __restrict__ Vt, u16* __restrict__ Aout) {
    const int tid = threadIdx.x;
    const int lane = tid & 63, wave = tid >> 6;  // wave 0..3
    const int lr = lane & 15, lg = lane >> 4;
    const int bid = blockIdx.x;                  // 0..1023
    const int swz = (bid & 7) * 128 + (bid >> 3);
    const int bh = swz >> 4;     // 0..63
    const int bx = swz & 15;     // 0..15
    const int b = bh >> 4, h = bh & 15;
    const size_t base = (size_t)bh << 17;  // bh * 2048 * 64

    const int qb_hi = 16 + bx;
    const int qb_lo = 15 - bx;

    __shared__ u16 Ks[2][64 * 64];     // K tile  [kv_local][d], chunk-swizzled
    __shared__ u16 Vs[2][64 * 64];     // Vt tile [d][kv_local], chunk-swizzled
    __shared__ u16 Ps[4][16 * 64];     // per-wave P scratch, chunk-XOR-swizzled

    // subtile q-bases: 0 = hi slice, 1 = lo slice (16 rows each)
    int qbase[2];
    qbase[0] = qb_hi * 64 + wave * 16;
    qbase[1] = qb_lo * 64 + wave * 16;

    bf16x8 qf[2][2];
#pragma unroll
    for (int st = 0; st < 2; ++st) {
        const u16* p = Q + base + (size_t)(qbase[st] + lr) * 64;
        qf[st][0] = *(const bf16x8*)(p + lg * 8);
        qf[st][1] = *(const bf16x8*)(p + 32 + lg * 8);
    }

    f32x4 o[2][4];
#pragma unroll
    for (int st = 0; st < 2; ++st)
#pragma unroll
        for (int dt = 0; dt < 4; ++dt) o[st][dt] = {0.f, 0.f, 0.f, 0.f};
    float m_[2] = {-INFINITY, -INFINITY};
    float l_[2] = {0.f, 0.f};

    // staging geometry (kt-invariant): thread stages 16B chunks.
    // dest (linear): byte f = (tid + rep*256)*16 -> row = f>>7, chunk c =
    // (f>>4)&7.  source chunk cc = c ^ (row&7)  (rule 21 pre-swizzle).
    const int f0 = tid * 16;
    const int row0 = f0 >> 7, c0 = (f0 >> 4) & 7;
    const int cc0 = c0 ^ (row0 & 7);
    const int f1 = (tid + 256) * 16;
    const int row1 = f1 >> 7, c1 = (f1 >> 4) & 7;
    const int cc1 = c1 ^ (row1 & 7);

    const int xr = lr & 7;  // read-side XOR key

    auto stage = [&](int sel, int kt) {
        const size_t krow = base + (size_t)(kt * 64) * 64;
        __builtin_amdgcn_global_load_lds(
            (const __attribute__((address_space(1))) void*)(Kg + krow + (size_t)row0 * 64 + cc0 * 8),
            (__attribute__((address_space(3))) void*)(&Ks[sel][tid * 8]), 16, 0, 0);
        __builtin_amdgcn_global_load_lds(
            (const __attribute__((address_space(1))) void*)(Kg + krow + (size_t)row1 * 64 + cc1 * 8),
            (__attribute__((address_space(3))) void*)(&Ks[sel][2048 + tid * 8]), 16, 0, 0);
        __builtin_amdgcn_global_load_lds(
            (const __attribute__((address_space(1))) void*)(Vt + base + (size_t)row0 * 2048 + kt * 64 + cc0 * 8),
            (__attribute__((address_space(3))) void*)(&Vs[sel][tid * 8]), 16, 0, 0);
        __builtin_amdgcn_global_load_lds(
            (const __attribute__((address_space(1))) void*)(Vt + base + (size_t)row1 * 2048 + kt * 64 + cc1 * 8),
            (__attribute__((address_space(3))) void*)(&Vs[sel][2048 + tid * 8]), 16, 0, 0);
    };

    auto process = [&](int sel, int st, bool diag, int kt) {
        // S^T[kv][q] = K * Q^T  (kv = kt*64 + rt*16 + lg*4 + reg, q = lr)
        f32x4 s[4];
#pragma unroll
        for (int rt = 0; rt < 4; ++rt) {
            const int krow = rt * 16 + lr;
            const bf16x8 k0 = *(const bf16x8*)&Ks[sel][krow * 64 + ((lg) ^ xr) * 8];
            const bf16x8 k1 = *(const bf16x8*)&Ks[sel][krow * 64 + ((lg + 4) ^ xr) * 8];
            f32x4 z = {0.f, 0.f, 0.f, 0.f};
            z = MFMA16(k0, qf[st][0], z);
            z = MFMA16(k1, qf[st][1], z);
            s[rt] = z;
        }
        if (diag) {
            const int q_glob = qbase[st] + lr;
#pragma unroll
            for (int rt = 0; rt < 4; ++rt)
#pragma unroll
                for (int r = 0; r < 4; ++r) {
                    const int kv = kt * 64 + rt * 16 + lg * 4 + r;
                    if (kv > q_glob) s[rt][r] = -INFINITY;
                }
        }
        // rmax via max3-friendly triples
        const float t0 = fmaxf(fmaxf(s[0][0], s[0][1]), s[0][2]);
        const float t1 = fmaxf(fmaxf(s[0][3], s[1][0]), s[1][1]);
        const float t2 = fmaxf(fmaxf(s[1][2], s[1][3]), s[2][0]);
        const float t3 = fmaxf(fmaxf(s[2][1], s[2][2]), s[2][3]);
        const float t4 = fmaxf(fmaxf(s[3][0], s[3][1]), s[3][2]);
        float rmax = fmaxf(fmaxf(fmaxf(t0, t1), t2), fmaxf(fmaxf(t3, t4), s[3][3]));
        rmax = fmaxf(rmax, __shfl_xor(rmax, 16));
        rmax = fmaxf(rmax, __shfl_xor(rmax, 32));

        if (!__all(rmax <= m_[st])) {  // exact skip: max didn't grow -> alpha==1
            const float m_new = fmaxf(m_[st], rmax);
            const float alpha = exp2f(m_[st] - m_new);
            float aq[4];
#pragma unroll
            for (int r = 0; r < 4; ++r) aq[r] = __shfl(alpha, (lane & 48) + lg * 4 + r);
#pragma unroll
            for (int dt = 0; dt < 4; ++dt)
#pragma unroll
                for (int r = 0; r < 4; ++r) o[st][dt][r] *= aq[r];
            l_[st] *= alpha;
            m_[st] = m_new;
        }

#pragma unroll
        for (int rt = 0; rt < 4; ++rt)
#pragma unroll
            for (int r = 0; r < 4; ++r) s[rt][r] = exp2f(s[rt][r] - m_[st]);
        // pairwise rsum tree
        const float u0 = (s[0][0] + s[0][1]) + (s[0][2] + s[0][3]);
        const float u1 = (s[1][0] + s[1][1]) + (s[1][2] + s[1][3]);
        const float u2 = (s[2][0] + s[2][1]) + (s[2][2] + s[2][3]);
        const float u3 = (s[3][0] + s[3][1]) + (s[3][2] + s[3][3]);
        float rsum = (u0 + u1) + (u2 + u3);
        rsum += __shfl_xor(rsum, 16);
        rsum += __shfl_xor(rsum, 32);
        l_[st] += rsum;

        // P (C-layout) -> LDS (XOR-swizzled) via v_cvt_pk_bf16_f32:
        // w = {lo: bf16(a), hi: bf16(b)} -> mem u16[0]=a, u16[1]=b (LE) --
        // same byte layout as the old bf16x4 path, 1 instr per pair (RNE).
        u16* psb = &Ps[wave][0];
#pragma unroll
        for (int rt = 0; rt < 4; ++rt) {
            unsigned w0, w1;
            asm("v_cvt_pk_bf16_f32 %0, %1, %2" : "=v"(w0) : "v"(s[rt][0]), "v"(s[rt][1]));
            asm("v_cvt_pk_bf16_f32 %0, %1, %2" : "=v"(w1) : "v"(s[rt][2]), "v"(s[rt][3]));
            uint2 w; w.x = w0; w.y = w1;
            *(uint2*)&psb[lr * 64 + (((rt * 2 + (lg >> 1)) ^ xr) << 3) + ((lg & 1) << 2)] = w;
        }

        const bf16x8 pf0 = *(const bf16x8*)&psb[lr * 64 + ((lg ^ xr) << 3)];
        const bf16x8 pf1 = *(const bf16x8*)&psb[lr * 64 + (((4 + lg) ^ xr) << 3)];
#pragma unroll
        for (int dt = 0; dt < 4; ++dt) {
            const int vrow = dt * 16 + lr;
            const bf16x8 v0 = *(const bf16x8*)&Vs[sel][vrow * 64 + ((lg) ^ xr) * 8];
            const bf16x8 v1 = *(const bf16x8*)&Vs[sel][vrow * 64 + ((lg + 4) ^ xr) * 8];
            o[st][dt] = MFMA16(pf0, v0, o[st][dt]);
            o[st][dt] = MFMA16(pf1, v1, o[st][dt]);
        }
    };

    stage(0, 0);
    for (int kt = 0; kt <= qb_hi; ++kt) {
        const int cur = kt & 1;
        __syncthreads();  // vmcnt(0) drain precedes barrier -> buf[cur] ready;
                          // all waves done reading buf[cur^1]
        if (kt < qb_hi) stage(cur ^ 1, kt + 1);
        process(cur, 0, kt == qb_hi, kt);
        if (kt <= qb_lo) process(cur, 1, kt == qb_lo, kt);
    }

#pragma unroll
    for (int st = 0; st < 2; ++st) {
        const float linv = 1.f / l_[st];
        float lq[4];
#pragma unroll
        for (int r = 0; r < 4; ++r) lq[r] = __shfl(linv, (lane & 48) + lg * 4 + r);
#pragma unroll
        for (int dt = 0; dt < 4; ++dt)
#pragma unroll
            for (int r = 0; r < 4; ++r) {
                const int t = qbase[st] + lg * 4 + r;
                Aout[(((size_t)(b << 11) + t) << 10) + h * 64 + dt * 16 + lr] =
                    f2bf(o[st][dt][r] * lq[r]);
            }
    }
}

// ---------------------------------------------------------------------------
extern "C" void kernel_launch(void* const* d_in, const int* in_sizes, int n_in,
                              void* d_out, int out_size, void* d_ws, size_t ws_size,
                              hipStream_t stream) {
    (void)in_sizes; (void)n_in; (void)out_size; (void)ws_size;
    const float* x    = (const float*)d_in[0];
    const float* Wqkv = (const float*)d_in[2];
    const float* bqkv = (const float*)d_in[3];
    const float* Wout = (const float*)d_in[4];
    const float* bout = (const float*)d_in[5];
    float* out = (float*)d_out;

    char* ws = (char*)d_ws;
    u16* WqkvT = (u16*)(ws);                    //  6 MB: [3072][1024] bf16
    u16* WoutT = (u16*)(ws + 6291456);          //  2 MB: [1024][1024] bf16
    u16* xb    = (u16*)(ws + 8388608);          // 16 MB: [8192][1024] bf16
    u16* Qb    = (u16*)(ws + 25165824);         // 16 MB: [BH][T][D]
    u16* Kb    = (u16*)(ws + 41943040);         // 16 MB: [BH][T][D]
    u16* Vtb   = (u16*)(ws + 58720256);         // 16 MB: [BH][D][T]
    u16* Ab    = (u16*)(ws + 75497472);         // 16 MB: [B][T][C]

    castk<<<dim3(4096), 256, 0, stream>>>(x, xb);
    tkern<<<dim3(16 * 48), 256, 0, stream>>>(Wqkv, WqkvT, 1024, 3072);
    tkern<<<dim3(16 * 16), 256, 0, stream>>>(Wout, WoutT, 1024, 1024);
    gemm_k<0><<<dim3(64 * 24), 256, 0, stream>>>(xb, WqkvT, bqkv, Qb, Kb, Vtb, nullptr);
    flash_attn<<<dim3(1024), 256, 0, stream>>>(Qb, Kb, Vtb, Ab);
    gemm_k<1><<<dim3(64 * 8), 256, 0, stream>>>(Ab, WoutT, bout, nullptr, nullptr, nullptr, out);
}